// Round 1
// baseline (298.397 us; speedup 1.0000x reference)
//
#include <hip/hip_runtime.h>
#include <cstdint>
#include <cstddef>

// BitLinear inference, round 3: 256x256-tile i8 MFMA GEMM with the verified
// 8-phase-style counted-vmcnt pipeline (T2 both-sides XOR swizzle + T3/T4
// double-buffered stage with vmcnt(8) gates + T5 setprio), replacing the
// serial-stage 128x128 2-barrier structure.
//
// ws layout (bytes):
//   [0       .. 16)        red[4] = {sum_w, sumabs_w, sum_b, sumabs_b}
//   [1024    .. 132096)    x_scale[32768] f32
//   [132096  .. 1180672)   w_q int8 [1024*1024]
//   [1180672 .. 34735104)  x_q int8 [32768*1024]

typedef __attribute__((ext_vector_type(4))) int int4v;

static constexpr int DIM = 1024;    // inner dim K (bytes per i8 row)
static constexpr int OUTF = 1024;   // output features N
static constexpr int MROWS = 32768; // B*S
static constexpr float INV_WN = 1.0f / (1024.0f * 1024.0f);
static constexpr float INV_BN = 1.0f / 1024.0f;

#define OFF_XSCALE 1024
#define OFF_WQ 132096
#define OFF_XQ 1180672

__device__ inline float wave_sum(float v) {
#pragma unroll
  for (int off = 32; off; off >>= 1) v += __shfl_xor(v, off);
  return v;
}
__device__ inline float wave_max(float v) {
#pragma unroll
  for (int off = 32; off; off >>= 1) v = fmaxf(v, __shfl_xor(v, off));
  return v;
}

// ---------------------------------------------------------------- reductions
__global__ __launch_bounds__(256) void reduce_wb(const float* __restrict__ w,
                                                 const float* __restrict__ b,
                                                 float* __restrict__ red) {
  __shared__ float ss[4], sa[4];
  const int t = threadIdx.x;
  const int lane = t & 63, wv = t >> 6;
  float s = 0.0f, a = 0.0f;
  const float4* w4 = (const float4*)w;
  const int idx = blockIdx.x * 256 + t;
#pragma unroll
  for (int i = 0; i < 4; ++i) {
    float4 v = w4[idx + i * 65536];
    s += (v.x + v.y) + (v.z + v.w);
    a += (fabsf(v.x) + fabsf(v.y)) + (fabsf(v.z) + fabsf(v.w));
  }
  s = wave_sum(s);
  a = wave_sum(a);
  if (lane == 0) { ss[wv] = s; sa[wv] = a; }
  __syncthreads();
  if (t == 0) atomicAdd(&red[0], (ss[0] + ss[1]) + (ss[2] + ss[3]));
  if (t == 1) atomicAdd(&red[1], (sa[0] + sa[1]) + (sa[2] + sa[3]));
  if (blockIdx.x == 0) {
    __syncthreads();  // block-uniform branch, safe
    float4 v = ((const float4*)b)[t];
    float s2 = (v.x + v.y) + (v.z + v.w);
    float a2 = (fabsf(v.x) + fabsf(v.y)) + (fabsf(v.z) + fabsf(v.w));
    s2 = wave_sum(s2);
    a2 = wave_sum(a2);
    if (lane == 0) { ss[wv] = s2; sa[wv] = a2; }
    __syncthreads();
    if (t == 0) {
      red[2] = (ss[0] + ss[1]) + (ss[2] + ss[3]);
      red[3] = (sa[0] + sa[1]) + (sa[2] + sa[3]);
    }
  }
}

// ---------------------------------------------------------------- weight quant
__global__ __launch_bounds__(256) void quant_w(const float* __restrict__ w,
                                               const float* __restrict__ red,
                                               signed char* __restrict__ wq) {
  const float wmean = red[0] * INV_WN;
  const int idx = blockIdx.x * 256 + threadIdx.x;
  float4 v = ((const float4*)w)[idx];
  int q0, q1, q2, q3;
  float d;
  d = v.x - wmean; q0 = d > 0.f ? 1 : (d < 0.f ? -1 : 0);
  d = v.y - wmean; q1 = d > 0.f ? 1 : (d < 0.f ? -1 : 0);
  d = v.z - wmean; q2 = d > 0.f ? 1 : (d < 0.f ? -1 : 0);
  d = v.w - wmean; q3 = d > 0.f ? 1 : (d < 0.f ? -1 : 0);
  const int pk = (q0 & 0xff) | ((q1 & 0xff) << 8) | ((q2 & 0xff) << 16) | ((q3 & 0xff) << 24);
  ((int*)wq)[idx] = pk;
}

// ---------------------------------------------------------------- activation quant
// one wave per row; 16 floats/lane in registers; no __syncthreads
__global__ __launch_bounds__(256) void quant_x(const float* __restrict__ x,
                                               signed char* __restrict__ xq,
                                               float* __restrict__ xscale) {
  const int wv = threadIdx.x >> 6;
  const int lane = threadIdx.x & 63;
  const int row = blockIdx.x * 4 + wv;
  const float4* xr = (const float4*)(x + (size_t)row * DIM);
  float4 v[4];
  float ss = 0.0f, ma = 0.0f;
#pragma unroll
  for (int it = 0; it < 4; ++it) {
    v[it] = xr[it * 64 + lane];
    ss += v[it].x * v[it].x + v[it].y * v[it].y + v[it].z * v[it].z + v[it].w * v[it].w;
    ma = fmaxf(ma, fmaxf(fmaxf(fabsf(v[it].x), fabsf(v[it].y)),
                         fmaxf(fabsf(v[it].z), fabsf(v[it].w))));
  }
  ss = wave_sum(ss);
  ma = wave_max(ma);

  const float l2 = sqrtf(ss);
  const float inv = 0.03125f / fmaxf(l2, 1e-12f);       // dim_scale / max(l2,eps)
  const float scale = 127.0f / fmaxf(ma * inv, 1e-5f);  // per-token int8 scale
  const float f = inv * scale;

  int* outp = (int*)(xq + (size_t)row * DIM);
#pragma unroll
  for (int it = 0; it < 4; ++it) {
    const int q0 = (int)fminf(fmaxf(rintf(v[it].x * f), -128.f), 127.f);
    const int q1 = (int)fminf(fmaxf(rintf(v[it].y * f), -128.f), 127.f);
    const int q2 = (int)fminf(fmaxf(rintf(v[it].z * f), -128.f), 127.f);
    const int q3 = (int)fminf(fmaxf(rintf(v[it].w * f), -128.f), 127.f);
    outp[it * 64 + lane] =
        (q0 & 0xff) | ((q1 & 0xff) << 8) | ((q2 & 0xff) << 16) | ((q3 & 0xff) << 24);
  }
  if (lane == 0) xscale[row] = scale;
}

// ---------------------------------------------------------------- GEMM (i8)
// 256x256 tile, K-tile = 128 B, 8 waves (2M x 4N), per-wave 128x64 output.
// Pipeline per K-tile: stage next tile (8x global_load_lds) -> counted
// s_waitcnt vmcnt(8) -> raw s_barrier -> 4 quadrant phases of
// {12x ds_read_b128 ; s_barrier ; setprio(1) 16x MFMA setprio(0) ; s_barrier}.
// NO __syncthreads in the K-loop (it drains vmcnt(0) = the m97 stall).
// LDS XOR swizzle byte^=((row&7)<<4): linear global_load_lds dest +
// inverse-swizzled per-lane GLOBAL source + swizzled ds_read (rule 21) =>
// wave64 b128 reads at the 8-addr/bank hardware optimum (was 16-way).
__global__ __launch_bounds__(512, 2) void gemm_i8(
    const signed char* __restrict__ Aq,  // [M, K] i8
    const signed char* __restrict__ Wq,  // [N, K] i8
    const float* __restrict__ bias,
    const float* __restrict__ red,
    const float* __restrict__ xscale,
    float* __restrict__ out) {
  __shared__ signed char As[2][256 * 128];  // 64 KB (double-buffered A tile)
  __shared__ signed char Bs[2][256 * 128];  // 64 KB

  const int t = threadIdx.x;
  const int lane = t & 63;
  const int wv = t >> 6;       // 0..7
  const int quad = lane >> 4;  // 0..3
  const int r16 = lane & 15;
  const int wr = wv >> 2;      // 0..1  M-half of tile
  const int wc = wv & 3;       // 0..3  N-quarter of tile

  // bijective XCD swizzle (512 blocks, 64/XCD); bn fastest inside an XCD so
  // the 4 blocks sharing one A panel (256KB xq) land on the same L2.
  const int orig = blockIdx.x;
  const int swz = (orig & 7) * 64 + (orig >> 3);
  const int bn = swz & 3;
  const int bm = swz >> 2;

  const signed char* Ab = Aq + (size_t)bm * 256 * DIM;
  const signed char* Bb = Wq + (size_t)bn * 256 * DIM;

  const int ldsoff = lane * 16;
  const int row8 = lane >> 3;                           // row within 8-row block
  const int sw16 = (((lane & 7) ^ row8) << 4);          // inverse-swizzled src byte

  int4v acc[8][4] = {};

// stage one K-tile (tt) of A and B into buffer dd: 8 global_load_lds / thread
#define STAGE(tt, dd)                                                            \
  do {                                                                           \
    const size_t koff_ = (size_t)(tt) * 128 + sw16;                              \
    _Pragma("unroll") for (int i_ = 0; i_ < 4; ++i_) {                           \
      const int blk_ = wv * 4 + i_; /* 0..31: 8 rows of 128B each */             \
      const size_t roff_ = (size_t)(blk_ * 8 + row8) * DIM + koff_;              \
      __builtin_amdgcn_global_load_lds(                                          \
          (const __attribute__((address_space(1))) void*)(Ab + roff_),           \
          (__attribute__((address_space(3))) void*)(&As[dd][blk_ * 1024 + ldsoff]), \
          16, 0, 0);                                                             \
      __builtin_amdgcn_global_load_lds(                                          \
          (const __attribute__((address_space(1))) void*)(Bb + roff_),           \
          (__attribute__((address_space(3))) void*)(&Bs[dd][blk_ * 1024 + ldsoff]), \
          16, 0, 0);                                                             \
    }                                                                            \
  } while (0)

// one quadrant phase: 8 A-frags + 4 B-frags (b128, swizzled), 16 MFMA
#define PHASE(mq, nq, cc)                                                        \
  do {                                                                           \
    int4v af[4][2], bf[2][2];                                                    \
    const int swr_ = (r16 & 7) << 4;                                             \
    _Pragma("unroll") for (int i_ = 0; i_ < 4; ++i_) {                           \
      const int r_ = wr * 128 + ((mq)*4 + i_) * 16 + r16;                        \
      _Pragma("unroll") for (int s_ = 0; s_ < 2; ++s_)                           \
          af[i_][s_] = *(const int4v*)&As[cc][r_ * 128 +                         \
                                             ((s_ * 64 + quad * 16) ^ swr_)];    \
    }                                                                            \
    _Pragma("unroll") for (int j_ = 0; j_ < 2; ++j_) {                           \
      const int r_ = wc * 64 + ((nq)*2 + j_) * 16 + r16;                         \
      _Pragma("unroll") for (int s_ = 0; s_ < 2; ++s_)                           \
          bf[j_][s_] = *(const int4v*)&Bs[cc][r_ * 128 +                         \
                                             ((s_ * 64 + quad * 16) ^ swr_)];    \
    }                                                                            \
    asm volatile("s_barrier" ::: "memory");                                      \
    __builtin_amdgcn_s_setprio(1);                                               \
    _Pragma("unroll") for (int i_ = 0; i_ < 4; ++i_)                             \
        _Pragma("unroll") for (int j_ = 0; j_ < 2; ++j_) {                       \
      acc[(mq)*4 + i_][(nq)*2 + j_] = __builtin_amdgcn_mfma_i32_16x16x64_i8(     \
          af[i_][0], bf[j_][0], acc[(mq)*4 + i_][(nq)*2 + j_], 0, 0, 0);         \
      acc[(mq)*4 + i_][(nq)*2 + j_] = __builtin_amdgcn_mfma_i32_16x16x64_i8(     \
          af[i_][1], bf[j_][1], acc[(mq)*4 + i_][(nq)*2 + j_], 0, 0, 0);         \
    }                                                                            \
    __builtin_amdgcn_s_setprio(0);                                               \
    asm volatile("s_barrier" ::: "memory");                                      \
  } while (0)

#define COMPUTE(cc) \
  PHASE(0, 0, cc);  \
  PHASE(1, 0, cc);  \
  PHASE(0, 1, cc);  \
  PHASE(1, 1, cc)

  STAGE(0, 0);
#pragma unroll 1
  for (int tp = 0; tp < 4; ++tp) {
    // even tile (2*tp) in buf0: prefetch odd tile into buf1 (just vacated),
    // then wait only for buf0's 8 loads (vmcnt(8) = counted, never 0).
    STAGE(2 * tp + 1, 1);
    asm volatile("s_waitcnt vmcnt(8)" ::: "memory");
    asm volatile("s_barrier" ::: "memory");
    COMPUTE(0);
    // odd tile (2*tp+1) in buf1: prefetch next even tile into buf0.
    if (tp < 3) {
      STAGE(2 * tp + 2, 0);
      asm volatile("s_waitcnt vmcnt(8)" ::: "memory");
    } else {
      asm volatile("s_waitcnt vmcnt(0)" ::: "memory");
    }
    asm volatile("s_barrier" ::: "memory");
    COMPUTE(1);
  }
#undef COMPUTE
#undef PHASE
#undef STAGE

  // epilogue: ternary bias + dequant
  const float wscale = red[1] * INV_WN;
  const float bscale = red[3] * INV_BN;
  const float bmean = red[2] * INV_BN;
  const float wb = wscale * bscale;

  int bq[4];
#pragma unroll
  for (int j = 0; j < 4; ++j) {
    const float bd = bias[bn * 256 + wc * 64 + j * 16 + r16] - bmean;
    bq[j] = bd > 0.f ? 1 : (bd < 0.f ? -1 : 0);
  }

#pragma unroll
  for (int i = 0; i < 8; ++i) {
    const int mg = bm * 256 + wr * 128 + i * 16 + quad * 4;
    float rec[4];
#pragma unroll
    for (int rr = 0; rr < 4; ++rr) rec[rr] = 1.0f / (wb * xscale[mg + rr]);
#pragma unroll
    for (int j = 0; j < 4; ++j) {
      float* po = out + (size_t)mg * OUTF + bn * 256 + wc * 64 + j * 16 + r16;
#pragma unroll
      for (int rr = 0; rr < 4; ++rr)
        po[(size_t)rr * OUTF] = (float)(acc[i][j][rr] + bq[j]) * rec[rr];
    }
  }
}

extern "C" void kernel_launch(void* const* d_in, const int* in_sizes, int n_in,
                              void* d_out, int out_size, void* d_ws, size_t ws_size,
                              hipStream_t stream) {
  const float* x = (const float*)d_in[0];
  const float* w = (const float*)d_in[1];
  const float* b = (const float*)d_in[2];
  float* out = (float*)d_out;
  char* ws = (char*)d_ws;

  float* red = (float*)ws;
  float* xscale = (float*)(ws + OFF_XSCALE);
  signed char* wq = (signed char*)(ws + OFF_WQ);
  signed char* xq = (signed char*)(ws + OFF_XQ);

  hipMemsetAsync(red, 0, 4 * sizeof(float), stream);
  reduce_wb<<<256, 256, 0, stream>>>(w, b, red);
  quant_w<<<1024, 256, 0, stream>>>(w, red, wq);
  quant_x<<<MROWS / 4, 256, 0, stream>>>(x, xq, xscale);
  gemm_i8<<<512, 512, 0, stream>>>(xq, wq, b, red, xscale, out);
}

// Round 2
// 293.309 us; speedup vs baseline: 1.0173x; 1.0173x over previous
//
#include <hip/hip_runtime.h>
#include <cstdint>
#include <cstddef>

// BitLinear inference, round 4: dedup the GEMM's LDS fragment reads.
// Round-3 structure re-read every A/B fragment twice (4 quadrant phases x
// 12 ds_read_b128 = 48 reads/wave/tile; 24 unique). Per-CU per K-tile that
// put the LDS pipe (~3072 cyc) above the MFMA pipe (~2616 cyc). This round:
// load all 8 B-frags once per tile, A-frags once per M-half, 2 compute
// phases -> 24 reads/wave/tile (~1536 LDS cyc) => MFMA-bound. Barriers
// per tile 9 -> 5. Pipeline (counted vmcnt(8), dbuf, setprio) unchanged.
//
// ws layout (bytes):
//   [0       .. 16)        red[4] = {sum_w, sumabs_w, sum_b, sumabs_b}
//   [1024    .. 132096)    x_scale[32768] f32
//   [132096  .. 1180672)   w_q int8 [1024*1024]
//   [1180672 .. 34735104)  x_q int8 [32768*1024]

typedef __attribute__((ext_vector_type(4))) int int4v;

static constexpr int DIM = 1024;    // inner dim K (bytes per i8 row)
static constexpr int OUTF = 1024;   // output features N
static constexpr int MROWS = 32768; // B*S
static constexpr float INV_WN = 1.0f / (1024.0f * 1024.0f);
static constexpr float INV_BN = 1.0f / 1024.0f;

#define OFF_XSCALE 1024
#define OFF_WQ 132096
#define OFF_XQ 1180672

__device__ inline float wave_sum(float v) {
#pragma unroll
  for (int off = 32; off; off >>= 1) v += __shfl_xor(v, off);
  return v;
}
__device__ inline float wave_max(float v) {
#pragma unroll
  for (int off = 32; off; off >>= 1) v = fmaxf(v, __shfl_xor(v, off));
  return v;
}

// ---------------------------------------------------------------- reductions
__global__ __launch_bounds__(256) void reduce_wb(const float* __restrict__ w,
                                                 const float* __restrict__ b,
                                                 float* __restrict__ red) {
  __shared__ float ss[4], sa[4];
  const int t = threadIdx.x;
  const int lane = t & 63, wv = t >> 6;
  float s = 0.0f, a = 0.0f;
  const float4* w4 = (const float4*)w;
  const int idx = blockIdx.x * 256 + t;
#pragma unroll
  for (int i = 0; i < 4; ++i) {
    float4 v = w4[idx + i * 65536];
    s += (v.x + v.y) + (v.z + v.w);
    a += (fabsf(v.x) + fabsf(v.y)) + (fabsf(v.z) + fabsf(v.w));
  }
  s = wave_sum(s);
  a = wave_sum(a);
  if (lane == 0) { ss[wv] = s; sa[wv] = a; }
  __syncthreads();
  if (t == 0) atomicAdd(&red[0], (ss[0] + ss[1]) + (ss[2] + ss[3]));
  if (t == 1) atomicAdd(&red[1], (sa[0] + sa[1]) + (sa[2] + sa[3]));
  if (blockIdx.x == 0) {
    __syncthreads();  // block-uniform branch, safe
    float4 v = ((const float4*)b)[t];
    float s2 = (v.x + v.y) + (v.z + v.w);
    float a2 = (fabsf(v.x) + fabsf(v.y)) + (fabsf(v.z) + fabsf(v.w));
    s2 = wave_sum(s2);
    a2 = wave_sum(a2);
    if (lane == 0) { ss[wv] = s2; sa[wv] = a2; }
    __syncthreads();
    if (t == 0) {
      red[2] = (ss[0] + ss[1]) + (ss[2] + ss[3]);
      red[3] = (sa[0] + sa[1]) + (sa[2] + sa[3]);
    }
  }
}

// ---------------------------------------------------------------- weight quant
__global__ __launch_bounds__(256) void quant_w(const float* __restrict__ w,
                                               const float* __restrict__ red,
                                               signed char* __restrict__ wq) {
  const float wmean = red[0] * INV_WN;
  const int idx = blockIdx.x * 256 + threadIdx.x;
  float4 v = ((const float4*)w)[idx];
  int q0, q1, q2, q3;
  float d;
  d = v.x - wmean; q0 = d > 0.f ? 1 : (d < 0.f ? -1 : 0);
  d = v.y - wmean; q1 = d > 0.f ? 1 : (d < 0.f ? -1 : 0);
  d = v.z - wmean; q2 = d > 0.f ? 1 : (d < 0.f ? -1 : 0);
  d = v.w - wmean; q3 = d > 0.f ? 1 : (d < 0.f ? -1 : 0);
  const int pk = (q0 & 0xff) | ((q1 & 0xff) << 8) | ((q2 & 0xff) << 16) | ((q3 & 0xff) << 24);
  ((int*)wq)[idx] = pk;
}

// ---------------------------------------------------------------- activation quant
// one wave per row; 16 floats/lane in registers; no __syncthreads
__global__ __launch_bounds__(256) void quant_x(const float* __restrict__ x,
                                               signed char* __restrict__ xq,
                                               float* __restrict__ xscale) {
  const int wv = threadIdx.x >> 6;
  const int lane = threadIdx.x & 63;
  const int row = blockIdx.x * 4 + wv;
  const float4* xr = (const float4*)(x + (size_t)row * DIM);
  float4 v[4];
  float ss = 0.0f, ma = 0.0f;
#pragma unroll
  for (int it = 0; it < 4; ++it) {
    v[it] = xr[it * 64 + lane];
    ss += v[it].x * v[it].x + v[it].y * v[it].y + v[it].z * v[it].z + v[it].w * v[it].w;
    ma = fmaxf(ma, fmaxf(fmaxf(fabsf(v[it].x), fabsf(v[it].y)),
                         fmaxf(fabsf(v[it].z), fabsf(v[it].w))));
  }
  ss = wave_sum(ss);
  ma = wave_max(ma);

  const float l2 = sqrtf(ss);
  const float inv = 0.03125f / fmaxf(l2, 1e-12f);       // dim_scale / max(l2,eps)
  const float scale = 127.0f / fmaxf(ma * inv, 1e-5f);  // per-token int8 scale
  const float f = inv * scale;

  int* outp = (int*)(xq + (size_t)row * DIM);
#pragma unroll
  for (int it = 0; it < 4; ++it) {
    const int q0 = (int)fminf(fmaxf(rintf(v[it].x * f), -128.f), 127.f);
    const int q1 = (int)fminf(fmaxf(rintf(v[it].y * f), -128.f), 127.f);
    const int q2 = (int)fminf(fmaxf(rintf(v[it].z * f), -128.f), 127.f);
    const int q3 = (int)fminf(fmaxf(rintf(v[it].w * f), -128.f), 127.f);
    outp[it * 64 + lane] =
        (q0 & 0xff) | ((q1 & 0xff) << 8) | ((q2 & 0xff) << 16) | ((q3 & 0xff) << 24);
  }
  if (lane == 0) xscale[row] = scale;
}

// ---------------------------------------------------------------- GEMM (i8)
// 256x256 tile, K-tile = 128 B, 8 waves (2M x 4N), per-wave 128x64 output.
// Per K-tile: stage next tile (8x global_load_lds) -> counted s_waitcnt
// vmcnt(8) -> s_barrier -> {load 8 B-frags once; 2 M-half phases of
// {load 8 A-frags ; s_barrier ; setprio(1) 32x MFMA setprio(0) ; s_barrier}}.
// 24 unique ds_read_b128 per wave per tile (was 48). No __syncthreads in
// the K-loop (it drains vmcnt(0) = the m97 stall). LDS XOR swizzle
// byte^=((row&7)<<4): linear global_load_lds dest + inverse-swizzled
// per-lane GLOBAL source + swizzled ds_read (rule 21).
__global__ __launch_bounds__(512, 2) void gemm_i8(
    const signed char* __restrict__ Aq,  // [M, K] i8
    const signed char* __restrict__ Wq,  // [N, K] i8
    const float* __restrict__ bias,
    const float* __restrict__ red,
    const float* __restrict__ xscale,
    float* __restrict__ out) {
  __shared__ signed char As[2][256 * 128];  // 64 KB (double-buffered A tile)
  __shared__ signed char Bs[2][256 * 128];  // 64 KB

  const int t = threadIdx.x;
  const int lane = t & 63;
  const int wv = t >> 6;       // 0..7
  const int quad = lane >> 4;  // 0..3
  const int r16 = lane & 15;
  const int wr = wv >> 2;      // 0..1  M-half of tile
  const int wc = wv & 3;       // 0..3  N-quarter of tile

  // bijective XCD swizzle (512 blocks, 64/XCD); bn fastest inside an XCD so
  // the 4 blocks sharing one A panel (256KB xq) land on the same L2.
  const int orig = blockIdx.x;
  const int swz = (orig & 7) * 64 + (orig >> 3);
  const int bn = swz & 3;
  const int bm = swz >> 2;

  const signed char* Ab = Aq + (size_t)bm * 256 * DIM;
  const signed char* Bb = Wq + (size_t)bn * 256 * DIM;

  const int ldsoff = lane * 16;
  const int row8 = lane >> 3;                           // row within 8-row block
  const int sw16 = (((lane & 7) ^ row8) << 4);          // inverse-swizzled src byte

  int4v acc[8][4] = {};

// stage one K-tile (tt) of A and B into buffer dd: 8 global_load_lds / thread
#define STAGE(tt, dd)                                                            \
  do {                                                                           \
    const size_t koff_ = (size_t)(tt) * 128 + sw16;                              \
    _Pragma("unroll") for (int i_ = 0; i_ < 4; ++i_) {                           \
      const int blk_ = wv * 4 + i_; /* 0..31: 8 rows of 128B each */             \
      const size_t roff_ = (size_t)(blk_ * 8 + row8) * DIM + koff_;              \
      __builtin_amdgcn_global_load_lds(                                          \
          (const __attribute__((address_space(1))) void*)(Ab + roff_),           \
          (__attribute__((address_space(3))) void*)(&As[dd][blk_ * 1024 + ldsoff]), \
          16, 0, 0);                                                             \
      __builtin_amdgcn_global_load_lds(                                          \
          (const __attribute__((address_space(1))) void*)(Bb + roff_),           \
          (__attribute__((address_space(3))) void*)(&Bs[dd][blk_ * 1024 + ldsoff]), \
          16, 0, 0);                                                             \
    }                                                                            \
  } while (0)

// one K-tile of compute: B-frags read ONCE, A-frags once per M-half.
#define COMPUTE(cc)                                                              \
  do {                                                                           \
    const int swr_ = (r16 & 7) << 4;                                             \
    int4v bf[4][2];                                                              \
    _Pragma("unroll") for (int j_ = 0; j_ < 4; ++j_) {                           \
      const int r_ = wc * 64 + j_ * 16 + r16;                                    \
      _Pragma("unroll") for (int s_ = 0; s_ < 2; ++s_)                           \
          bf[j_][s_] = *(const int4v*)&Bs[cc][r_ * 128 +                         \
                                              ((s_ * 64 + quad * 16) ^ swr_)];   \
    }                                                                            \
    _Pragma("unroll") for (int mq_ = 0; mq_ < 2; ++mq_) {                        \
      int4v af[4][2];                                                            \
      _Pragma("unroll") for (int i_ = 0; i_ < 4; ++i_) {                         \
        const int r_ = wr * 128 + mq_ * 64 + i_ * 16 + r16;                      \
        _Pragma("unroll") for (int s_ = 0; s_ < 2; ++s_)                         \
            af[i_][s_] = *(const int4v*)&As[cc][r_ * 128 +                       \
                                                ((s_ * 64 + quad * 16) ^ swr_)]; \
      }                                                                          \
      asm volatile("s_barrier" ::: "memory");                                    \
      __builtin_amdgcn_s_setprio(1);                                             \
      _Pragma("unroll") for (int i_ = 0; i_ < 4; ++i_)                           \
          _Pragma("unroll") for (int j_ = 0; j_ < 4; ++j_) {                     \
        acc[mq_ * 4 + i_][j_] = __builtin_amdgcn_mfma_i32_16x16x64_i8(           \
            af[i_][0], bf[j_][0], acc[mq_ * 4 + i_][j_], 0, 0, 0);               \
        acc[mq_ * 4 + i_][j_] = __builtin_amdgcn_mfma_i32_16x16x64_i8(           \
            af[i_][1], bf[j_][1], acc[mq_ * 4 + i_][j_], 0, 0, 0);               \
      }                                                                          \
      __builtin_amdgcn_s_setprio(0);                                             \
      asm volatile("s_barrier" ::: "memory");                                    \
    }                                                                            \
  } while (0)

  STAGE(0, 0);
#pragma unroll 1
  for (int tp = 0; tp < 4; ++tp) {
    // even tile (2*tp) in buf0: prefetch odd tile into buf1 (just vacated),
    // then wait only for buf0's 8 loads (vmcnt(8) = counted, never 0).
    STAGE(2 * tp + 1, 1);
    asm volatile("s_waitcnt vmcnt(8)" ::: "memory");
    asm volatile("s_barrier" ::: "memory");
    COMPUTE(0);
    // odd tile (2*tp+1) in buf1: prefetch next even tile into buf0.
    if (tp < 3) {
      STAGE(2 * tp + 2, 0);
      asm volatile("s_waitcnt vmcnt(8)" ::: "memory");
    } else {
      asm volatile("s_waitcnt vmcnt(0)" ::: "memory");
    }
    asm volatile("s_barrier" ::: "memory");
    COMPUTE(1);
  }
#undef COMPUTE
#undef STAGE

  // epilogue: ternary bias + dequant
  const float wscale = red[1] * INV_WN;
  const float bscale = red[3] * INV_BN;
  const float bmean = red[2] * INV_BN;
  const float wb = wscale * bscale;

  int bq[4];
#pragma unroll
  for (int j = 0; j < 4; ++j) {
    const float bd = bias[bn * 256 + wc * 64 + j * 16 + r16] - bmean;
    bq[j] = bd > 0.f ? 1 : (bd < 0.f ? -1 : 0);
  }

#pragma unroll
  for (int i = 0; i < 8; ++i) {
    const int mg = bm * 256 + wr * 128 + i * 16 + quad * 4;
    float rec[4];
#pragma unroll
    for (int rr = 0; rr < 4; ++rr) rec[rr] = 1.0f / (wb * xscale[mg + rr]);
#pragma unroll
    for (int j = 0; j < 4; ++j) {
      float* po = out + (size_t)mg * OUTF + bn * 256 + wc * 64 + j * 16 + r16;
#pragma unroll
      for (int rr = 0; rr < 4; ++rr)
        po[(size_t)rr * OUTF] = (float)(acc[i][j][rr] + bq[j]) * rec[rr];
    }
  }
}

extern "C" void kernel_launch(void* const* d_in, const int* in_sizes, int n_in,
                              void* d_out, int out_size, void* d_ws, size_t ws_size,
                              hipStream_t stream) {
  const float* x = (const float*)d_in[0];
  const float* w = (const float*)d_in[1];
  const float* b = (const float*)d_in[2];
  float* out = (float*)d_out;
  char* ws = (char*)d_ws;

  float* red = (float*)ws;
  float* xscale = (float*)(ws + OFF_XSCALE);
  signed char* wq = (signed char*)(ws + OFF_WQ);
  signed char* xq = (signed char*)(ws + OFF_XQ);

  hipMemsetAsync(red, 0, 4 * sizeof(float), stream);
  reduce_wb<<<256, 256, 0, stream>>>(w, b, red);
  quant_w<<<1024, 256, 0, stream>>>(w, red, wq);
  quant_x<<<MROWS / 4, 256, 0, stream>>>(x, xq, xscale);
  gemm_i8<<<dim3(512), 512, 0, stream>>>(xq, wq, b, red, xscale, out);
}

// Round 3
// 285.032 us; speedup vs baseline: 1.0469x; 1.0290x over previous
//
#include <hip/hip_runtime.h>
#include <cstdint>
#include <cstddef>

// BitLinear inference, round 5: 32x32x32 i8 MFMA (+12% matrix rate vs
// 16x16x64) + barrier diet (5 -> 2 per K-tile). Round-4's dedup made the
// GEMM MFMA-issue/barrier-bound; this round attacks exactly that.
// Fragment geometry: lane holds 16 K-consecutive bytes, row = lane&31,
// K-half = lane>>5 (the 32-row analog of the proven quad=lane>>4 16x16
// mapping). C/D: col=lane&31, row=(reg&3)+8*(reg>>2)+4*(lane>>5) [m74/m101].
//
// ws layout (bytes):
//   [0       .. 16)        red[4] = {sum_w, sumabs_w, sum_b, sumabs_b}
//   [1024    .. 132096)    x_scale[32768] f32
//   [132096  .. 1180672)   w_q int8 [1024*1024]
//   [1180672 .. 34735104)  x_q int8 [32768*1024]

typedef __attribute__((ext_vector_type(4))) int int4v;
typedef __attribute__((ext_vector_type(16))) int int16v;

static constexpr int DIM = 1024;    // inner dim K (bytes per i8 row)
static constexpr int OUTF = 1024;   // output features N
static constexpr int MROWS = 32768; // B*S
static constexpr float INV_WN = 1.0f / (1024.0f * 1024.0f);
static constexpr float INV_BN = 1.0f / 1024.0f;

#define OFF_XSCALE 1024
#define OFF_WQ 132096
#define OFF_XQ 1180672

__device__ inline float wave_sum(float v) {
#pragma unroll
  for (int off = 32; off; off >>= 1) v += __shfl_xor(v, off);
  return v;
}
__device__ inline float wave_max(float v) {
#pragma unroll
  for (int off = 32; off; off >>= 1) v = fmaxf(v, __shfl_xor(v, off));
  return v;
}

// ---------------------------------------------------------------- reductions
__global__ __launch_bounds__(256) void reduce_wb(const float* __restrict__ w,
                                                 const float* __restrict__ b,
                                                 float* __restrict__ red) {
  __shared__ float ss[4], sa[4];
  const int t = threadIdx.x;
  const int lane = t & 63, wv = t >> 6;
  float s = 0.0f, a = 0.0f;
  const float4* w4 = (const float4*)w;
  const int idx = blockIdx.x * 256 + t;
#pragma unroll
  for (int i = 0; i < 4; ++i) {
    float4 v = w4[idx + i * 65536];
    s += (v.x + v.y) + (v.z + v.w);
    a += (fabsf(v.x) + fabsf(v.y)) + (fabsf(v.z) + fabsf(v.w));
  }
  s = wave_sum(s);
  a = wave_sum(a);
  if (lane == 0) { ss[wv] = s; sa[wv] = a; }
  __syncthreads();
  if (t == 0) atomicAdd(&red[0], (ss[0] + ss[1]) + (ss[2] + ss[3]));
  if (t == 1) atomicAdd(&red[1], (sa[0] + sa[1]) + (sa[2] + sa[3]));
  if (blockIdx.x == 0) {
    __syncthreads();  // block-uniform branch, safe
    float4 v = ((const float4*)b)[t];
    float s2 = (v.x + v.y) + (v.z + v.w);
    float a2 = (fabsf(v.x) + fabsf(v.y)) + (fabsf(v.z) + fabsf(v.w));
    s2 = wave_sum(s2);
    a2 = wave_sum(a2);
    if (lane == 0) { ss[wv] = s2; sa[wv] = a2; }
    __syncthreads();
    if (t == 0) {
      red[2] = (ss[0] + ss[1]) + (ss[2] + ss[3]);
      red[3] = (sa[0] + sa[1]) + (sa[2] + sa[3]);
    }
  }
}

// ---------------------------------------------------------------- weight quant
__global__ __launch_bounds__(256) void quant_w(const float* __restrict__ w,
                                               const float* __restrict__ red,
                                               signed char* __restrict__ wq) {
  const float wmean = red[0] * INV_WN;
  const int idx = blockIdx.x * 256 + threadIdx.x;
  float4 v = ((const float4*)w)[idx];
  int q0, q1, q2, q3;
  float d;
  d = v.x - wmean; q0 = d > 0.f ? 1 : (d < 0.f ? -1 : 0);
  d = v.y - wmean; q1 = d > 0.f ? 1 : (d < 0.f ? -1 : 0);
  d = v.z - wmean; q2 = d > 0.f ? 1 : (d < 0.f ? -1 : 0);
  d = v.w - wmean; q3 = d > 0.f ? 1 : (d < 0.f ? -1 : 0);
  const int pk = (q0 & 0xff) | ((q1 & 0xff) << 8) | ((q2 & 0xff) << 16) | ((q3 & 0xff) << 24);
  ((int*)wq)[idx] = pk;
}

// ---------------------------------------------------------------- activation quant
// one wave per row; 16 floats/lane in registers; no __syncthreads
__global__ __launch_bounds__(256) void quant_x(const float* __restrict__ x,
                                               signed char* __restrict__ xq,
                                               float* __restrict__ xscale) {
  const int wv = threadIdx.x >> 6;
  const int lane = threadIdx.x & 63;
  const int row = blockIdx.x * 4 + wv;
  const float4* xr = (const float4*)(x + (size_t)row * DIM);
  float4 v[4];
  float ss = 0.0f, ma = 0.0f;
#pragma unroll
  for (int it = 0; it < 4; ++it) {
    v[it] = xr[it * 64 + lane];
    ss += v[it].x * v[it].x + v[it].y * v[it].y + v[it].z * v[it].z + v[it].w * v[it].w;
    ma = fmaxf(ma, fmaxf(fmaxf(fabsf(v[it].x), fabsf(v[it].y)),
                         fmaxf(fabsf(v[it].z), fabsf(v[it].w))));
  }
  ss = wave_sum(ss);
  ma = wave_max(ma);

  const float l2 = sqrtf(ss);
  const float inv = 0.03125f / fmaxf(l2, 1e-12f);       // dim_scale / max(l2,eps)
  const float scale = 127.0f / fmaxf(ma * inv, 1e-5f);  // per-token int8 scale
  const float f = inv * scale;

  int* outp = (int*)(xq + (size_t)row * DIM);
#pragma unroll
  for (int it = 0; it < 4; ++it) {
    const int q0 = (int)fminf(fmaxf(rintf(v[it].x * f), -128.f), 127.f);
    const int q1 = (int)fminf(fmaxf(rintf(v[it].y * f), -128.f), 127.f);
    const int q2 = (int)fminf(fmaxf(rintf(v[it].z * f), -128.f), 127.f);
    const int q3 = (int)fminf(fmaxf(rintf(v[it].w * f), -128.f), 127.f);
    outp[it * 64 + lane] =
        (q0 & 0xff) | ((q1 & 0xff) << 8) | ((q2 & 0xff) << 16) | ((q3 & 0xff) << 24);
  }
  if (lane == 0) xscale[row] = scale;
}

// ---------------------------------------------------------------- GEMM (i8)
// 256x256 tile, K-tile = 128 B (4 K-steps of 32), 8 waves (2M x 4N),
// per-wave 128x64 output as 4x2 fragments of 32x32.
// Per K-tile: STAGE(next) -> counted s_waitcnt vmcnt(8) -> s_barrier ->
// {8 B-frag + 16 A-frag ds_read_b128 (each read ONCE); 4 M-frag groups of
// 8 MFMA under setprio(1)} -> s_barrier (buffer-reuse guard). 2 barriers
// per tile (was 5). No __syncthreads in the K-loop (vmcnt(0) drain = the
// m97 stall). LDS XOR swizzle byte^=((row&7)<<4): linear global_load_lds
// dest + inverse-swizzled per-lane GLOBAL source + swizzled ds_read.
__global__ __launch_bounds__(512, 2) void gemm_i8(
    const signed char* __restrict__ Aq,  // [M, K] i8
    const signed char* __restrict__ Wq,  // [N, K] i8
    const float* __restrict__ bias,
    const float* __restrict__ red,
    const float* __restrict__ xscale,
    float* __restrict__ out) {
  __shared__ signed char As[2][256 * 128];  // 64 KB (double-buffered A tile)
  __shared__ signed char Bs[2][256 * 128];  // 64 KB

  const int t = threadIdx.x;
  const int lane = t & 63;
  const int wv = t >> 6;       // 0..7
  const int l31 = lane & 31;
  const int hi = lane >> 5;    // K-half selector for 32x32 fragments
  const int wr = wv >> 2;      // 0..1  M-half of tile
  const int wc = wv & 3;       // 0..3  N-quarter of tile

  // bijective XCD swizzle (512 blocks, 64/XCD); bn fastest inside an XCD so
  // the 4 blocks sharing one A panel (256KB xq) land on the same L2.
  const int orig = blockIdx.x;
  const int swz = (orig & 7) * 64 + (orig >> 3);
  const int bn = swz & 3;
  const int bm = swz >> 2;

  const signed char* Ab = Aq + (size_t)bm * 256 * DIM;
  const signed char* Bb = Wq + (size_t)bn * 256 * DIM;

  const int ldsoff = lane * 16;
  const int row8 = lane >> 3;                   // row within 8-row block
  const int sw16 = (((lane & 7) ^ row8) << 4);  // inverse-swizzled src byte

  int16v acc[4][2] = {};

// stage one K-tile (tt) of A and B into buffer dd: 8 global_load_lds / thread
#define STAGE(tt, dd)                                                            \
  do {                                                                           \
    const size_t koff_ = (size_t)(tt) * 128 + sw16;                              \
    _Pragma("unroll") for (int i_ = 0; i_ < 4; ++i_) {                           \
      const int blk_ = wv * 4 + i_; /* 0..31: 8 rows of 128B each */             \
      const size_t roff_ = (size_t)(blk_ * 8 + row8) * DIM + koff_;              \
      __builtin_amdgcn_global_load_lds(                                          \
          (const __attribute__((address_space(1))) void*)(Ab + roff_),           \
          (__attribute__((address_space(3))) void*)(&As[dd][blk_ * 1024 + ldsoff]), \
          16, 0, 0);                                                             \
      __builtin_amdgcn_global_load_lds(                                          \
          (const __attribute__((address_space(1))) void*)(Bb + roff_),           \
          (__attribute__((address_space(3))) void*)(&Bs[dd][blk_ * 1024 + ldsoff]), \
          16, 0, 0);                                                             \
    }                                                                            \
  } while (0)

// one K-tile: 8 B-frags + 16 A-frags read once; 32 MFMA (4 mf x 2 nf x 4 ks)
#define COMPUTE(cc)                                                              \
  do {                                                                           \
    const int swr_ = (lane & 7) << 4; /* row&7 == lane&7 for A and B rows */     \
    int4v bf[2][4];                                                              \
    _Pragma("unroll") for (int nf_ = 0; nf_ < 2; ++nf_) {                        \
      const int r_ = wc * 64 + nf_ * 32 + l31;                                   \
      _Pragma("unroll") for (int ks_ = 0; ks_ < 4; ++ks_)                        \
          bf[nf_][ks_] = *(const int4v*)&Bs[cc][r_ * 128 +                       \
                                                ((ks_ * 32 + hi * 16) ^ swr_)];  \
    }                                                                            \
    _Pragma("unroll") for (int mf_ = 0; mf_ < 4; ++mf_) {                        \
      int4v af[4];                                                               \
      const int r_ = wr * 128 + mf_ * 32 + l31;                                  \
      _Pragma("unroll") for (int ks_ = 0; ks_ < 4; ++ks_)                        \
          af[ks_] = *(const int4v*)&As[cc][r_ * 128 +                            \
                                           ((ks_ * 32 + hi * 16) ^ swr_)];       \
      __builtin_amdgcn_s_setprio(1);                                             \
      _Pragma("unroll") for (int nf_ = 0; nf_ < 2; ++nf_)                        \
          _Pragma("unroll") for (int ks_ = 0; ks_ < 4; ++ks_)                    \
              acc[mf_][nf_] = __builtin_amdgcn_mfma_i32_32x32x32_i8(             \
                  af[ks_], bf[nf_][ks_], acc[mf_][nf_], 0, 0, 0);                \
      __builtin_amdgcn_s_setprio(0);                                             \
    }                                                                            \
  } while (0)

  STAGE(0, 0);
#pragma unroll 1
  for (int tp = 0; tp < 4; ++tp) {
    // even tile (2*tp) in buf0: prefetch odd tile into buf1, wait only for
    // buf0's 8 loads (vmcnt(8) = counted, never 0 until the final tile).
    STAGE(2 * tp + 1, 1);
    asm volatile("s_waitcnt vmcnt(8)" ::: "memory");
    asm volatile("s_barrier" ::: "memory");  // all waves' tile-2tp loads landed
    COMPUTE(0);
    asm volatile("s_barrier" ::: "memory");  // buf0 reads done before re-stage
    if (tp < 3) {
      STAGE(2 * tp + 2, 0);
      asm volatile("s_waitcnt vmcnt(8)" ::: "memory");
    } else {
      asm volatile("s_waitcnt vmcnt(0)" ::: "memory");
    }
    asm volatile("s_barrier" ::: "memory");  // all waves' tile-2tp+1 loads landed
    COMPUTE(1);
    asm volatile("s_barrier" ::: "memory");  // buf1 reads done before re-stage
  }
#undef COMPUTE
#undef STAGE

  // epilogue: ternary bias + dequant
  // C/D layout (32x32): col = lane&31, row = (reg&3) + 8*(reg>>2) + 4*hi
  const float wscale = red[1] * INV_WN;
  const float bscale = red[3] * INV_BN;
  const float bmean = red[2] * INV_BN;
  const float wb = wscale * bscale;

  int bq[2];
#pragma unroll
  for (int nf = 0; nf < 2; ++nf) {
    const float bd = bias[bn * 256 + wc * 64 + nf * 32 + l31] - bmean;
    bq[nf] = bd > 0.f ? 1 : (bd < 0.f ? -1 : 0);
  }

#pragma unroll
  for (int mf = 0; mf < 4; ++mf) {
#pragma unroll
    for (int rq = 0; rq < 4; ++rq) {
      const int mg = bm * 256 + wr * 128 + mf * 32 + rq * 8 + hi * 4;
      const float4 xs = *(const float4*)&xscale[mg];
      float rec[4];
      rec[0] = 1.0f / (wb * xs.x);
      rec[1] = 1.0f / (wb * xs.y);
      rec[2] = 1.0f / (wb * xs.z);
      rec[3] = 1.0f / (wb * xs.w);
#pragma unroll
      for (int nf = 0; nf < 2; ++nf) {
        const int n = bn * 256 + wc * 64 + nf * 32 + l31;
#pragma unroll
        for (int rr = 0; rr < 4; ++rr) {
          const int reg = rq * 4 + rr;  // reg>>2==rq, reg&3==rr
          out[(size_t)(mg + rr) * OUTF + n] =
              (float)(acc[mf][nf][reg] + bq[nf]) * rec[rr];
        }
      }
    }
  }
}

extern "C" void kernel_launch(void* const* d_in, const int* in_sizes, int n_in,
                              void* d_out, int out_size, void* d_ws, size_t ws_size,
                              hipStream_t stream) {
  const float* x = (const float*)d_in[0];
  const float* w = (const float*)d_in[1];
  const float* b = (const float*)d_in[2];
  float* out = (float*)d_out;
  char* ws = (char*)d_ws;

  float* red = (float*)ws;
  float* xscale = (float*)(ws + OFF_XSCALE);
  signed char* wq = (signed char*)(ws + OFF_WQ);
  signed char* xq = (signed char*)(ws + OFF_XQ);

  hipMemsetAsync(red, 0, 4 * sizeof(float), stream);
  reduce_wb<<<256, 256, 0, stream>>>(w, b, red);
  quant_w<<<1024, 256, 0, stream>>>(w, red, wq);
  quant_x<<<MROWS / 4, 256, 0, stream>>>(x, xq, xscale);
  gemm_i8<<<dim3(512), 512, 0, stream>>>(xq, wq, b, red, xscale, out);
}

// Round 5
// 274.664 us; speedup vs baseline: 1.0864x; 1.0377x over previous
//
#include <hip/hip_runtime.h>
#include <cstdint>
#include <cstddef>

// BitLinear inference, round 6 (resubmit after infra flake): sync diet.
// (1) GEMM: 1 barrier per K-tile (was 2). Post-compute vmcnt(0) is near-free
//     (other buffer's loads had the whole compute phase to land); a single
//     barrier then certifies both "everyone done reading buf X" (re-stage
//     safe) and "everyone's buf Y loads landed" (compute safe). 16 -> 7
//     barriers per block.
// (2) No hipMemsetAsync + no global atomics: reduce_wb writes per-block
//     partials; quant_w blocks sum the 256 partials themselves (L2-hit) and
//     block 0 finalizes red[1]; reduce_wb block 0 finalizes bias red[2..3].
//
// ws layout (bytes):
//   [0       .. 16)        red[4] = {sum_w, sumabs_w, sum_b, sumabs_b}
//   [1024    .. 132096)    x_scale[32768] f32
//   [132096  .. 1180672)   w_q int8 [1024*1024]
//   [1180672 .. 34735104)  x_q int8 [32768*1024]
//   [34735104.. 34737152)  part[512] f32 (w partial sums: [0..256) sum,
//                          [256..512) sumabs)

typedef __attribute__((ext_vector_type(4))) int int4v;
typedef __attribute__((ext_vector_type(16))) int int16v;

static constexpr int DIM = 1024;    // inner dim K (bytes per i8 row)
static constexpr int OUTF = 1024;   // output features N
static constexpr int MROWS = 32768; // B*S
static constexpr float INV_WN = 1.0f / (1024.0f * 1024.0f);
static constexpr float INV_BN = 1.0f / 1024.0f;

#define OFF_XSCALE 1024
#define OFF_WQ 132096
#define OFF_XQ 1180672
#define OFF_PART 34735104

__device__ inline float wave_sum(float v) {
#pragma unroll
  for (int off = 32; off; off >>= 1) v += __shfl_xor(v, off);
  return v;
}
__device__ inline float wave_max(float v) {
#pragma unroll
  for (int off = 32; off; off >>= 1) v = fmaxf(v, __shfl_xor(v, off));
  return v;
}

// ---------------------------------------------------------------- reductions
// per-block partials to ws (no atomics, no memset needed); block 0 also
// finalizes the bias stats (red[2], red[3]).
__global__ __launch_bounds__(256) void reduce_wb(const float* __restrict__ w,
                                                 const float* __restrict__ b,
                                                 float* __restrict__ red,
                                                 float* __restrict__ part) {
  __shared__ float ss[4], sa[4];
  const int t = threadIdx.x;
  const int lane = t & 63, wv = t >> 6;
  float s = 0.0f, a = 0.0f;
  const float4* w4 = (const float4*)w;
  const int idx = blockIdx.x * 256 + t;
#pragma unroll
  for (int i = 0; i < 4; ++i) {
    float4 v = w4[idx + i * 65536];
    s += (v.x + v.y) + (v.z + v.w);
    a += (fabsf(v.x) + fabsf(v.y)) + (fabsf(v.z) + fabsf(v.w));
  }
  s = wave_sum(s);
  a = wave_sum(a);
  if (lane == 0) { ss[wv] = s; sa[wv] = a; }
  __syncthreads();
  if (t == 0) part[blockIdx.x] = (ss[0] + ss[1]) + (ss[2] + ss[3]);
  if (t == 1) part[256 + blockIdx.x] = (sa[0] + sa[1]) + (sa[2] + sa[3]);
  if (blockIdx.x == 0) {
    __syncthreads();  // block-uniform branch, safe
    float4 v = ((const float4*)b)[t];
    float s2 = (v.x + v.y) + (v.z + v.w);
    float a2 = (fabsf(v.x) + fabsf(v.y)) + (fabsf(v.z) + fabsf(v.w));
    s2 = wave_sum(s2);
    a2 = wave_sum(a2);
    if (lane == 0) { ss[wv] = s2; sa[wv] = a2; }
    __syncthreads();
    if (t == 0) {
      red[2] = (ss[0] + ss[1]) + (ss[2] + ss[3]);
      red[3] = (sa[0] + sa[1]) + (sa[2] + sa[3]);
    }
  }
}

// ---------------------------------------------------------------- weight quant
// each block derives wmean from the 256 partials (L2-hit, ~free);
// block 0 finalizes red[0], red[1] for the GEMM epilogue.
__global__ __launch_bounds__(256) void quant_w(const float* __restrict__ w,
                                               const float* __restrict__ part,
                                               float* __restrict__ red,
                                               signed char* __restrict__ wq) {
  __shared__ float smean;
  const int t = threadIdx.x;
  if (t < 64) {  // wave-uniform branch (wave 0)
    float s = 0.0f;
#pragma unroll
    for (int i = 0; i < 4; ++i) s += part[t * 4 + i];
    s = wave_sum(s);
    if (t == 0) smean = s * INV_WN;
    if (blockIdx.x == 0) {
      float a = 0.0f;
#pragma unroll
      for (int i = 0; i < 4; ++i) a += part[256 + t * 4 + i];
      a = wave_sum(a);
      if (t == 0) { red[0] = s; red[1] = a; }
    }
  }
  __syncthreads();
  const float wmean = smean;
  const int idx = blockIdx.x * 256 + t;
  float4 v = ((const float4*)w)[idx];
  int q0, q1, q2, q3;
  float d;
  d = v.x - wmean; q0 = d > 0.f ? 1 : (d < 0.f ? -1 : 0);
  d = v.y - wmean; q1 = d > 0.f ? 1 : (d < 0.f ? -1 : 0);
  d = v.z - wmean; q2 = d > 0.f ? 1 : (d < 0.f ? -1 : 0);
  d = v.w - wmean; q3 = d > 0.f ? 1 : (d < 0.f ? -1 : 0);
  const int pk = (q0 & 0xff) | ((q1 & 0xff) << 8) | ((q2 & 0xff) << 16) | ((q3 & 0xff) << 24);
  ((int*)wq)[idx] = pk;
}

// ---------------------------------------------------------------- activation quant
// one wave per row; 16 floats/lane in registers; no __syncthreads
__global__ __launch_bounds__(256) void quant_x(const float* __restrict__ x,
                                               signed char* __restrict__ xq,
                                               float* __restrict__ xscale) {
  const int wv = threadIdx.x >> 6;
  const int lane = threadIdx.x & 63;
  const int row = blockIdx.x * 4 + wv;
  const float4* xr = (const float4*)(x + (size_t)row * DIM);
  float4 v[4];
  float ss = 0.0f, ma = 0.0f;
#pragma unroll
  for (int it = 0; it < 4; ++it) {
    v[it] = xr[it * 64 + lane];
    ss += v[it].x * v[it].x + v[it].y * v[it].y + v[it].z * v[it].z + v[it].w * v[it].w;
    ma = fmaxf(ma, fmaxf(fmaxf(fabsf(v[it].x), fabsf(v[it].y)),
                         fmaxf(fabsf(v[it].z), fabsf(v[it].w))));
  }
  ss = wave_sum(ss);
  ma = wave_max(ma);

  const float l2 = sqrtf(ss);
  const float inv = 0.03125f / fmaxf(l2, 1e-12f);       // dim_scale / max(l2,eps)
  const float scale = 127.0f / fmaxf(ma * inv, 1e-5f);  // per-token int8 scale
  const float f = inv * scale;

  int* outp = (int*)(xq + (size_t)row * DIM);
#pragma unroll
  for (int it = 0; it < 4; ++it) {
    const int q0 = (int)fminf(fmaxf(rintf(v[it].x * f), -128.f), 127.f);
    const int q1 = (int)fminf(fmaxf(rintf(v[it].y * f), -128.f), 127.f);
    const int q2 = (int)fminf(fmaxf(rintf(v[it].z * f), -128.f), 127.f);
    const int q3 = (int)fminf(fmaxf(rintf(v[it].w * f), -128.f), 127.f);
    outp[it * 64 + lane] =
        (q0 & 0xff) | ((q1 & 0xff) << 8) | ((q2 & 0xff) << 16) | ((q3 & 0xff) << 24);
  }
  if (lane == 0) xscale[row] = scale;
}

// ---------------------------------------------------------------- GEMM (i8)
// 256x256 tile, K-tile = 128 B (4 K-steps of 32), 8 waves (2M x 4N),
// per-wave 128x64 output as 4x2 fragments of 32x32.
// Per K-tile: COMPUTE(cur) -> vmcnt(0) [other buf's loads landed; near-free,
// they had the whole compute phase] -> s_barrier [all done reading cur AND
// all verified other-buf loads] -> STAGE next into cur. ONE barrier/tile.
// No __syncthreads in the K-loop. LDS XOR swizzle byte^=((row&7)<<4):
// linear global_load_lds dest + inverse-swizzled per-lane GLOBAL source +
// swizzled ds_read (rule 21).
__global__ __launch_bounds__(512, 2) void gemm_i8(
    const signed char* __restrict__ Aq,  // [M, K] i8
    const signed char* __restrict__ Wq,  // [N, K] i8
    const float* __restrict__ bias,
    const float* __restrict__ red,
    const float* __restrict__ xscale,
    float* __restrict__ out) {
  __shared__ signed char As[2][256 * 128];  // 64 KB (double-buffered A tile)
  __shared__ signed char Bs[2][256 * 128];  // 64 KB

  const int t = threadIdx.x;
  const int lane = t & 63;
  const int wv = t >> 6;       // 0..7
  const int l31 = lane & 31;
  const int hi = lane >> 5;    // K-half selector for 32x32 fragments
  const int wr = wv >> 2;      // 0..1  M-half of tile
  const int wc = wv & 3;       // 0..3  N-quarter of tile

  // bijective XCD swizzle (512 blocks, 64/XCD); bn fastest inside an XCD so
  // the 4 blocks sharing one A panel (256KB xq) land on the same L2.
  const int orig = blockIdx.x;
  const int swz = (orig & 7) * 64 + (orig >> 3);
  const int bn = swz & 3;
  const int bm = swz >> 2;

  const signed char* Ab = Aq + (size_t)bm * 256 * DIM;
  const signed char* Bb = Wq + (size_t)bn * 256 * DIM;

  const int ldsoff = lane * 16;
  const int row8 = lane >> 3;                   // row within 8-row block
  const int sw16 = (((lane & 7) ^ row8) << 4);  // inverse-swizzled src byte

  int16v acc[4][2] = {};

// stage one K-tile (tt) of A and B into buffer dd: 8 global_load_lds / thread
#define STAGE(tt, dd)                                                            \
  do {                                                                           \
    const size_t koff_ = (size_t)(tt) * 128 + sw16;                              \
    _Pragma("unroll") for (int i_ = 0; i_ < 4; ++i_) {                           \
      const int blk_ = wv * 4 + i_; /* 0..31: 8 rows of 128B each */             \
      const size_t roff_ = (size_t)(blk_ * 8 + row8) * DIM + koff_;              \
      __builtin_amdgcn_global_load_lds(                                          \
          (const __attribute__((address_space(1))) void*)(Ab + roff_),           \
          (__attribute__((address_space(3))) void*)(&As[dd][blk_ * 1024 + ldsoff]), \
          16, 0, 0);                                                             \
      __builtin_amdgcn_global_load_lds(                                          \
          (const __attribute__((address_space(1))) void*)(Bb + roff_),           \
          (__attribute__((address_space(3))) void*)(&Bs[dd][blk_ * 1024 + ldsoff]), \
          16, 0, 0);                                                             \
    }                                                                            \
  } while (0)

// one K-tile: 8 B-frags + 16 A-frags read once; 32 MFMA (4 mf x 2 nf x 4 ks)
#define COMPUTE(cc)                                                              \
  do {                                                                           \
    const int swr_ = (lane & 7) << 4; /* row&7 == lane&7 for A and B rows */     \
    int4v bf[2][4];                                                              \
    _Pragma("unroll") for (int nf_ = 0; nf_ < 2; ++nf_) {                        \
      const int r_ = wc * 64 + nf_ * 32 + l31;                                   \
      _Pragma("unroll") for (int ks_ = 0; ks_ < 4; ++ks_)                        \
          bf[nf_][ks_] = *(const int4v*)&Bs[cc][r_ * 128 +                       \
                                                ((ks_ * 32 + hi * 16) ^ swr_)];  \
    }                                                                            \
    _Pragma("unroll") for (int mf_ = 0; mf_ < 4; ++mf_) {                        \
      int4v af[4];                                                               \
      const int r_ = wr * 128 + mf_ * 32 + l31;                                  \
      _Pragma("unroll") for (int ks_ = 0; ks_ < 4; ++ks_)                        \
          af[ks_] = *(const int4v*)&As[cc][r_ * 128 +                            \
                                           ((ks_ * 32 + hi * 16) ^ swr_)];       \
      __builtin_amdgcn_s_setprio(1);                                             \
      _Pragma("unroll") for (int nf_ = 0; nf_ < 2; ++nf_)                        \
          _Pragma("unroll") for (int ks_ = 0; ks_ < 4; ++ks_)                    \
              acc[mf_][nf_] = __builtin_amdgcn_mfma_i32_32x32x32_i8(             \
                  af[ks_], bf[nf_][ks_], acc[mf_][nf_], 0, 0, 0);                \
      __builtin_amdgcn_s_setprio(0);                                             \
    }                                                                            \
  } while (0)

  STAGE(0, 0);
  STAGE(1, 1);
  asm volatile("s_waitcnt vmcnt(8)" ::: "memory");  // own tile-0 loads landed
  asm volatile("s_barrier" ::: "memory");           // everyone's tile-0 landed
#pragma unroll 1
  for (int tp = 0; tp < 4; ++tp) {
    COMPUTE(0);                                      // tile 2tp (buf0)
    asm volatile("s_waitcnt vmcnt(0)" ::: "memory"); // own tile-(2tp+1) loads landed
    asm volatile("s_barrier" ::: "memory");          // all read buf0; all verified buf1
    if (tp < 3) STAGE(2 * tp + 2, 0);                // refill buf0 (safe)
    COMPUTE(1);                                      // tile 2tp+1 (buf1)
    if (tp < 3) {
      asm volatile("s_waitcnt vmcnt(0)" ::: "memory"); // own tile-(2tp+2) landed
      asm volatile("s_barrier" ::: "memory");          // all read buf1; all verified buf0
      STAGE(2 * tp + 3, 1);                            // refill buf1 (safe)
    }
  }
#undef COMPUTE
#undef STAGE

  // epilogue: ternary bias + dequant
  // C/D layout (32x32): col = lane&31, row = (reg&3) + 8*(reg>>2) + 4*hi
  const float wscale = red[1] * INV_WN;
  const float bscale = red[3] * INV_BN;
  const float bmean = red[2] * INV_BN;
  const float wb = wscale * bscale;

  int bq[2];
#pragma unroll
  for (int nf = 0; nf < 2; ++nf) {
    const float bd = bias[bn * 256 + wc * 64 + nf * 32 + l31] - bmean;
    bq[nf] = bd > 0.f ? 1 : (bd < 0.f ? -1 : 0);
  }

#pragma unroll
  for (int mf = 0; mf < 4; ++mf) {
#pragma unroll
    for (int rq = 0; rq < 4; ++rq) {
      const int mg = bm * 256 + wr * 128 + mf * 32 + rq * 8 + hi * 4;
      const float4 xs = *(const float4*)&xscale[mg];
      float rec[4];
      rec[0] = 1.0f / (wb * xs.x);
      rec[1] = 1.0f / (wb * xs.y);
      rec[2] = 1.0f / (wb * xs.z);
      rec[3] = 1.0f / (wb * xs.w);
#pragma unroll
      for (int nf = 0; nf < 2; ++nf) {
        const int n = bn * 256 + wc * 64 + nf * 32 + l31;
#pragma unroll
        for (int rr = 0; rr < 4; ++rr) {
          const int reg = rq * 4 + rr;  // reg>>2==rq, reg&3==rr
          out[(size_t)(mg + rr) * OUTF + n] =
              (float)(acc[mf][nf][reg] + bq[nf]) * rec[rr];
        }
      }
    }
  }
}

extern "C" void kernel_launch(void* const* d_in, const int* in_sizes, int n_in,
                              void* d_out, int out_size, void* d_ws, size_t ws_size,
                              hipStream_t stream) {
  const float* x = (const float*)d_in[0];
  const float* w = (const float*)d_in[1];
  const float* b = (const float*)d_in[2];
  float* out = (float*)d_out;
  char* ws = (char*)d_ws;

  float* red = (float*)ws;
  float* xscale = (float*)(ws + OFF_XSCALE);
  signed char* wq = (signed char*)(ws + OFF_WQ);
  signed char* xq = (signed char*)(ws + OFF_XQ);
  float* part = (float*)(ws + OFF_PART);

  reduce_wb<<<256, 256, 0, stream>>>(w, b, red, part);
  quant_w<<<1024, 256, 0, stream>>>(w, part, red, wq);
  quant_x<<<MROWS / 4, 256, 0, stream>>>(x, xq, xscale);
  gemm_i8<<<dim3(512), 512, 0, stream>>>(xq, wq, b, red, xscale, out);
}